// Round 1
// baseline (1750.070 us; speedup 1.0000x reference)
//
#include <hip/hip_runtime.h>
#include <cmath>

#define DIMN 4096
#define NHh 32
#define NKVv 8
#define HDd 128
#define PAST_ 4096
#define STOT 4104
#define NCH 16
#define CHUNK 257

// output section offsets (floats)
#define OUT_OFF ((size_t)0)
#define KI8_OFF ((size_t)262144)
#define KS_OFF  ((size_t)134742016)
#define VI8_OFF ((size_t)135792640)
#define VS_OFF  ((size_t)270272512)

// workspace offsets (floats)
#define WS_QKV ((size_t)0)         // 64 x 6144
#define WS_QR  ((size_t)393216)    // 262144
#define WS_KR  ((size_t)655360)    // 65536
#define WS_VR  ((size_t)720896)    // 65536
#define WS_ATT ((size_t)786432)    // 262144
#define WS_BIG ((size_t)1048576)   // 4259840 (gemm partials / Op+Ml)
#define WS_ML  (WS_BIG + (size_t)4194304)

__device__ __forceinline__ float clampq(float x) {
    return fminf(fmaxf(x, -127.0f), 127.0f);
}

// ---------------- GEMM: C(64 x N) = A(64 x K) @ [B1 | B2], split-K partials ----------------
__global__ __launch_bounds__(256) void gemm64(
    const float* __restrict__ A, int lda,
    const float* __restrict__ B1, int ldb1,
    const float* __restrict__ B2, int ldb2, int nsplit,
    int N, int kslice, float* __restrict__ Cp)
{
    __shared__ __align__(16) float xs[64 * 65];
    __shared__ __align__(16) float wsB[64 * 68];
    const int t = threadIdx.x;
    const int tx = t & 15, ty = t >> 4;
    const int n0 = blockIdx.x * 64;
    const int k0b = blockIdx.y * kslice;

    float4 acc[4];
#pragma unroll
    for (int i = 0; i < 4; ++i) acc[i] = make_float4(0.f, 0.f, 0.f, 0.f);

    for (int k0 = k0b; k0 < k0b + kslice; k0 += 64) {
#pragma unroll
        for (int i = 0; i < 16; ++i) {
            int idx = i * 256 + t;
            int r = idx >> 6, c = idx & 63;   // r: 0..63, c: 0..63
            // A tile: xs[m][kk], m=r, kk=c
            xs[r * 65 + c] = A[(size_t)r * lda + k0 + c];
            // B tile: wsB[kk][nn], kk=r, nn=c
            int col = n0 + c;
            float bv;
            if (col < nsplit) bv = B1[(size_t)(k0 + r) * ldb1 + col];
            else              bv = B2[(size_t)(k0 + r) * ldb2 + (col - nsplit)];
            wsB[r * 68 + c] = bv;
        }
        __syncthreads();
#pragma unroll 16
        for (int kk = 0; kk < 64; ++kk) {
            const float4 b4 = *(const float4*)&wsB[kk * 68 + tx * 4];
#pragma unroll
            for (int im = 0; im < 4; ++im) {
                float a = xs[(ty * 4 + im) * 65 + kk];
                acc[im].x += a * b4.x; acc[im].y += a * b4.y;
                acc[im].z += a * b4.z; acc[im].w += a * b4.w;
            }
        }
        __syncthreads();
    }
#pragma unroll
    for (int im = 0; im < 4; ++im) {
        int m = ty * 4 + im;
        *(float4*)&Cp[((size_t)blockIdx.y * 64 + m) * N + n0 + tx * 4] = acc[im];
    }
}

__global__ __launch_bounds__(256) void reduce8(const float* __restrict__ p,
                                               float* __restrict__ dst, int size)
{
    int i = blockIdx.x * 256 + threadIdx.x;
    if (i < size) {
        float s = 0.f;
#pragma unroll
        for (int k = 0; k < 8; ++k) s += p[(size_t)k * size + i];
        dst[i] = s;
    }
}

// ---------------- RoPE on Q ----------------
__global__ __launch_bounds__(128) void rope_q_kernel(const float* __restrict__ qkv,
                                                     float* __restrict__ Qr,
                                                     const int* __restrict__ startp)
{
    int blk = blockIdx.x;                 // 2048 = b*256 + tt*32 + h
    int h = blk & 31, tt = (blk >> 5) & 7, b = blk >> 8;
    int d = threadIdx.x;
    __shared__ float row[128];
    int bt = b * 8 + tt;
    float xv = qkv[(size_t)bt * 6144 + h * 128 + d];
    row[d] = xv;
    __syncthreads();
    int dh = d & 63;
    float e = (float)(2 * dh) * (1.0f / 128.0f);
    float invf = 1.0f / powf(10000.0f, e);
    float ang = (float)(startp[0] + tt) * invf;
    float c = cosf(ang), s = sinf(ang);
    float part = (d < 64) ? -row[d + 64] : row[d - 64];
    Qr[(((size_t)(b * 32 + h)) * 8 + tt) * 128 + d] = xv * c + part * s;
}

// ---------------- RoPE on new K, pass-through V, quantize new rows ----------------
__global__ __launch_bounds__(128) void kv_new_kernel(const float* __restrict__ qkv,
                                                     float* __restrict__ Kr,
                                                     float* __restrict__ Vr,
                                                     float* __restrict__ outb,
                                                     const int* __restrict__ startp)
{
    int blk = blockIdx.x;                 // 512 = b*64 + tt*8 + kv
    int kv = blk & 7, tt = (blk >> 3) & 7, b = blk >> 6;
    int d = threadIdx.x;
    __shared__ float row[128];
    __shared__ float red[128];
    int bt = b * 8 + tt;
    float kin = qkv[(size_t)bt * 6144 + 4096 + kv * 128 + d];
    float vin = qkv[(size_t)bt * 6144 + 5120 + kv * 128 + d];
    row[d] = kin;
    __syncthreads();
    int dh = d & 63;
    float e = (float)(2 * dh) * (1.0f / 128.0f);
    float invf = 1.0f / powf(10000.0f, e);
    float ang = (float)(startp[0] + tt) * invf;
    float c = cosf(ang), s = sinf(ang);
    float part = (d < 64) ? -row[d + 64] : row[d - 64];
    float kf = kin * c + part * s;
    int bkv = b * 8 + kv;
    Kr[((size_t)bkv * 8 + tt) * 128 + d] = kf;
    Vr[((size_t)bkv * 8 + tt) * 128 + d] = vin;
    int sidx = PAST_ + tt;

    // quantize k row
    red[d] = fabsf(kf);
    __syncthreads();
    for (int w = 64; w > 0; w >>= 1) {
        if (d < w) red[d] = fmaxf(red[d], red[d + w]);
        __syncthreads();
    }
    float sk = fmaxf(red[0] / 127.0f, 1e-8f);
    __syncthreads();
    float qk = clampq(rintf(kf / sk));
#pragma unroll
    for (int r = 0; r < 4; ++r) {
        size_t hh = (size_t)(b * 32 + kv * 4 + r);
        outb[KI8_OFF + (hh * STOT + sidx) * 128 + d] = qk;
        if (d == 0) outb[KS_OFF + hh * STOT + sidx] = sk;
    }
    // quantize v row
    red[d] = fabsf(vin);
    __syncthreads();
    for (int w = 64; w > 0; w >>= 1) {
        if (d < w) red[d] = fmaxf(red[d], red[d + w]);
        __syncthreads();
    }
    float sv = fmaxf(red[0] / 127.0f, 1e-8f);
    __syncthreads();
    float qv = clampq(rintf(vin / sv));
#pragma unroll
    for (int r = 0; r < 4; ++r) {
        size_t hh = (size_t)(b * 32 + kv * 4 + r);
        outb[VI8_OFF + (hh * STOT + sidx) * 128 + d] = qv;
        if (d == 0) outb[VS_OFF + hh * STOT + sidx] = sv;
    }
}

// ---------------- fused flash attention + past-KV requantization ----------------
__global__ __launch_bounds__(256) void attn_kernel(
    const float* __restrict__ Qr, const float* __restrict__ Kr, const float* __restrict__ Vr,
    const int* __restrict__ pk, const float* __restrict__ pks,
    const int* __restrict__ pv, const float* __restrict__ pvs,
    float* __restrict__ outb, float* __restrict__ Op, float* __restrict__ Ml)
{
    __shared__ __align__(16) float qs[32 * 132];
    __shared__ __align__(16) float kt[32 * 132];
    __shared__ __align__(16) float vt[32 * 132];
    __shared__ float ps[32 * 36];

    const int bkv = blockIdx.x;           // 64 = b*8+kv
    const int c = blockIdx.y;             // 16
    const int b = bkv >> 3, kv = bkv & 7;
    const int t = threadIdx.x;
    const int q = t >> 3, o = t & 7;

    // stage Q (vectorized): 32 rows x 128
#pragma unroll
    for (int i = 0; i < 4; ++i) {
        int idx = i * 256 + t;            // 0..1023 float4s
        int qq = idx >> 5, d4 = idx & 31;
        const float4 qv = *(const float4*)&Qr[(((size_t)(b * 32 + kv * 4 + (qq >> 3))) * 8 + (qq & 7)) * 128 + d4 * 4];
        *(float4*)&qs[qq * 132 + d4 * 4] = qv;
    }

    float O[16];
#pragma unroll
    for (int i = 0; i < 16; ++i) O[i] = 0.f;
    float m = -1e30f, l = 0.f;

    const int s_beg = c * CHUNK;
    const int s_end = min(s_beg + CHUNK, STOT);
    const float4* qs4 = (const float4*)qs;
    const float4* kt4 = (const float4*)kt;
    const float4* vt4 = (const float4*)vt;
    const float SC = 0.08838834764831845f; // 1/sqrt(128)

    for (int st = s_beg; st < s_end; st += 32) {
        const int nk = min(32, s_end - st);
        // ---- stage K/V tile (dequant past, copy new), vectorized int4/float4 ----
#pragma unroll
        for (int i = 0; i < 4; ++i) {
            int idx = i * 256 + t;        // 0..1023 -> 32 keys x 32 float4
            int key = idx >> 5, d4 = idx & 31;
            float4 kf = make_float4(0.f, 0.f, 0.f, 0.f);
            float4 vf = kf;
            int s = st + key;
            if (key < nk) {
                if (s < PAST_) {
                    size_t base = (size_t)bkv * PAST_ + s;
                    const int4 ik = *(const int4*)&pk[base * 128 + d4 * 4];
                    const int4 iv = *(const int4*)&pv[base * 128 + d4 * 4];
                    float sk_ = pks[base], sv_ = pvs[base];
                    kf = make_float4((float)ik.x * sk_, (float)ik.y * sk_, (float)ik.z * sk_, (float)ik.w * sk_);
                    vf = make_float4((float)iv.x * sv_, (float)iv.y * sv_, (float)iv.z * sv_, (float)iv.w * sv_);
                } else {
                    size_t rr = (size_t)bkv * 8 + (s - PAST_);
                    kf = *(const float4*)&Kr[rr * 128 + d4 * 4];
                    vf = *(const float4*)&Vr[rr * 128 + d4 * 4];
                }
            }
            *(float4*)&kt[key * 132 + d4 * 4] = kf;
            *(float4*)&vt[key * 132 + d4 * 4] = vf;
        }
        __syncthreads();

        // ---- requantize + write past rows (each row handled by one 8-lane group) ----
        {
            int key = q;
            int s = st + key;
            if (key < nk && s < PAST_) {
                float4 kvv[4], vvv[4];
#pragma unroll
                for (int i = 0; i < 4; ++i) {
                    kvv[i] = kt4[key * 33 + o * 4 + i];
                    vvv[i] = vt4[key * 33 + o * 4 + i];
                }
                float mk = 0.f, mv = 0.f;
#pragma unroll
                for (int i = 0; i < 4; ++i) {
                    mk = fmaxf(mk, fmaxf(fmaxf(fabsf(kvv[i].x), fabsf(kvv[i].y)), fmaxf(fabsf(kvv[i].z), fabsf(kvv[i].w))));
                    mv = fmaxf(mv, fmaxf(fmaxf(fabsf(vvv[i].x), fabsf(vvv[i].y)), fmaxf(fabsf(vvv[i].z), fabsf(vvv[i].w))));
                }
#pragma unroll
                for (int w = 1; w < 8; w <<= 1) {
                    mk = fmaxf(mk, __shfl_xor(mk, w, 8));
                    mv = fmaxf(mv, __shfl_xor(mv, w, 8));
                }
                float sk_ = fmaxf(mk / 127.0f, 1e-8f);
                float sv_ = fmaxf(mv / 127.0f, 1e-8f);
                float rk = 1.0f / sk_, rv = 1.0f / sv_;
                float4 qk4[4], qv4[4];
#pragma unroll
                for (int i = 0; i < 4; ++i) {
                    qk4[i] = make_float4(clampq(rintf(kvv[i].x * rk)), clampq(rintf(kvv[i].y * rk)),
                                         clampq(rintf(kvv[i].z * rk)), clampq(rintf(kvv[i].w * rk)));
                    qv4[i] = make_float4(clampq(rintf(vvv[i].x * rv)), clampq(rintf(vvv[i].y * rv)),
                                         clampq(rintf(vvv[i].z * rv)), clampq(rintf(vvv[i].w * rv)));
                }
#pragma unroll
                for (int r = 0; r < 4; ++r) {
                    size_t hh = (size_t)(b * 32 + kv * 4 + r);
                    size_t rowk = KI8_OFF + (hh * STOT + s) * 128 + o * 16;
                    size_t rowv = VI8_OFF + (hh * STOT + s) * 128 + o * 16;
#pragma unroll
                    for (int i = 0; i < 4; ++i) {
                        *(float4*)&outb[rowk + i * 4] = qk4[i];
                        *(float4*)&outb[rowv + i * 4] = qv4[i];
                    }
                    if (o == 0) {
                        outb[KS_OFF + hh * STOT + s] = sk_;
                        outb[VS_OFF + hh * STOT + s] = sv_;
                    }
                }
            }
        }

        // ---- scores: thread computes full 128-dots for keys o, o+8, o+16, o+24 ----
        float4 a0 = make_float4(0.f, 0.f, 0.f, 0.f), a1 = a0, a2 = a0, a3 = a0;
#pragma unroll 8
        for (int d4 = 0; d4 < 32; ++d4) {
            float4 qv = qs4[q * 33 + d4];
            float4 k0 = kt4[(o + 0) * 33 + d4];
            float4 k1 = kt4[(o + 8) * 33 + d4];
            float4 k2 = kt4[(o + 16) * 33 + d4];
            float4 k3 = kt4[(o + 24) * 33 + d4];
            a0.x += qv.x * k0.x; a0.y += qv.y * k0.y; a0.z += qv.z * k0.z; a0.w += qv.w * k0.w;
            a1.x += qv.x * k1.x; a1.y += qv.y * k1.y; a1.z += qv.z * k1.z; a1.w += qv.w * k1.w;
            a2.x += qv.x * k2.x; a2.y += qv.y * k2.y; a2.z += qv.z * k2.z; a2.w += qv.w * k2.w;
            a3.x += qv.x * k3.x; a3.y += qv.y * k3.y; a3.z += qv.z * k3.z; a3.w += qv.w * k3.w;
        }
        float s0 = ((a0.x + a0.y) + (a0.z + a0.w)) * SC;
        float s1 = ((a1.x + a1.y) + (a1.z + a1.w)) * SC;
        float s2 = ((a2.x + a2.y) + (a2.z + a2.w)) * SC;
        float s3 = ((a3.x + a3.y) + (a3.z + a3.w)) * SC;
        if (st + o + 0  >= s_end) s0 = -1e30f;
        if (st + o + 8  >= s_end) s1 = -1e30f;
        if (st + o + 16 >= s_end) s2 = -1e30f;
        if (st + o + 24 >= s_end) s3 = -1e30f;

        float mt = fmaxf(fmaxf(s0, s1), fmaxf(s2, s3));
#pragma unroll
        for (int w = 1; w < 8; w <<= 1) mt = fmaxf(mt, __shfl_xor(mt, w, 8));
        float mn = fmaxf(m, mt);
        float alpha = expf(m - mn);
        float p0 = expf(s0 - mn), p1 = expf(s1 - mn), p2 = expf(s2 - mn), p3 = expf(s3 - mn);
        float ls = (p0 + p1) + (p2 + p3);
#pragma unroll
        for (int w = 1; w < 8; w <<= 1) ls += __shfl_xor(ls, w, 8);
        l = l * alpha + ls;
        m = mn;
#pragma unroll
        for (int i = 0; i < 16; ++i) O[i] *= alpha;
        ps[q * 36 + o] = p0; ps[q * 36 + o + 8] = p1;
        ps[q * 36 + o + 16] = p2; ps[q * 36 + o + 24] = p3;
        __syncthreads();

        // ---- O += P @ V (thread owns its q's d-slice o*16..o*16+15) ----
#pragma unroll 8
        for (int j = 0; j < 32; ++j) {
            int jr = (j + o) & 31;
            float p = ps[q * 36 + jr];
#pragma unroll
            for (int i = 0; i < 4; ++i) {
                float4 v4 = vt4[jr * 33 + o * 4 + i];
                O[i * 4 + 0] += p * v4.x; O[i * 4 + 1] += p * v4.y;
                O[i * 4 + 2] += p * v4.z; O[i * 4 + 3] += p * v4.w;
            }
        }
        __syncthreads();
    }

    // epilogue: partial O, m, l
    size_t ob = ((size_t)c * 64 + bkv) * 4096 + q * 128 + o * 16;
#pragma unroll
    for (int i = 0; i < 4; ++i) {
        *(float4*)&Op[ob + i * 4] = make_float4(O[i * 4 + 0], O[i * 4 + 1], O[i * 4 + 2], O[i * 4 + 3]);
    }
    if (o == 0) {
        size_t mb = (((size_t)c * 64 + bkv) * 32 + q) * 2;
        Ml[mb] = m; Ml[mb + 1] = l;
    }
}

// ---------------- combine chunk partials -> attn (B,T,DIM) ----------------
__global__ __launch_bounds__(128) void combine_kernel(const float* __restrict__ Op,
                                                      const float* __restrict__ Ml,
                                                      float* __restrict__ attn)
{
    int blk = blockIdx.x;                 // 2048 = bkv*32 + q
    int d = threadIdx.x;
    int bkv = blk >> 5, q = blk & 31;
    float mv[16], lv[16];
    float M = -1e30f;
#pragma unroll
    for (int c = 0; c < 16; ++c) {
        size_t mb = (((size_t)c * 64 + bkv) * 32 + q) * 2;
        mv[c] = Ml[mb]; lv[c] = Ml[mb + 1];
        M = fmaxf(M, mv[c]);
    }
    float L = 0.f, Od = 0.f;
#pragma unroll
    for (int c = 0; c < 16; ++c) {
        float w = expf(mv[c] - M);
        L += w * lv[c];
        Od += w * Op[((size_t)c * 64 + bkv) * 4096 + q * 128 + d];
    }
    int b = bkv >> 3, kv = bkv & 7;
    int h = kv * 4 + (q >> 3), tt = q & 7;
    attn[((size_t)(b * 8 + tt)) * 4096 + h * 128 + d] = Od / L;
}

extern "C" void kernel_launch(void* const* d_in, const int* in_sizes, int n_in,
                              void* d_out, int out_size, void* d_ws, size_t ws_size,
                              hipStream_t stream) {
    const float* x   = (const float*)d_in[0];
    const float* Wq  = (const float*)d_in[1];
    const float* Wkv = (const float*)d_in[2];
    const float* Wo  = (const float*)d_in[3];
    const int*   pk  = (const int*)d_in[4];
    const float* pks = (const float*)d_in[5];
    const int*   pv  = (const int*)d_in[6];
    const float* pvs = (const float*)d_in[7];
    const int*   sp  = (const int*)d_in[8];
    float* outb = (float*)d_out;
    float* ws = (float*)d_ws;

    float* QKV = ws + WS_QKV;
    float* QR  = ws + WS_QR;
    float* KR  = ws + WS_KR;
    float* VR  = ws + WS_VR;
    float* ATT = ws + WS_ATT;
    float* BIG = ws + WS_BIG;
    float* ML  = ws + WS_ML;

    // 1. qkv = x @ [Wq | Wkv]  (64 x 6144), split-K 8
    gemm64<<<dim3(96, 8), 256, 0, stream>>>(x, DIMN, Wq, DIMN, Wkv, 2048, 4096, 6144, 512, BIG);
    reduce8<<<(393216 + 255) / 256, 256, 0, stream>>>(BIG, QKV, 393216);
    // 2. RoPE
    rope_q_kernel<<<2048, 128, 0, stream>>>(QKV, QR, sp);
    kv_new_kernel<<<512, 128, 0, stream>>>(QKV, KR, VR, outb, sp);
    // 3. fused flash attention + past-KV requant
    attn_kernel<<<dim3(64, 16), 256, 0, stream>>>(QR, KR, VR, pk, pks, pv, pvs, outb, BIG, ML);
    // 4. combine chunks
    combine_kernel<<<2048, 128, 0, stream>>>(BIG, ML, ATT);
    // 5. out = attn @ Wo, split-K 8
    gemm64<<<dim3(64, 8), 256, 0, stream>>>(ATT, DIMN, Wo, DIMN, (const float*)nullptr, 0, 4096, 4096, 512, BIG);
    reduce8<<<(262144 + 255) / 256, 256, 0, stream>>>(BIG, outb + OUT_OFF, 262144);
}